// Round 9
// baseline (989.338 us; speedup 1.0000x reference)
//
#include <hip/hip_runtime.h>
#include <math.h>

// T=1000, B=256, F_IN=13 x3 -> 39 features, H=100, 3H=300 (gate order r,z,n), 20 classes
#define T_STEPS 1000
#define BATCH   256
#define FIN     13
#define XDIM    39
#define HDIM    100
#define G3      300
#define NCLS    20
#define NTHR    960      // 3 thread-parts per gate row; parts are wave-aligned (5 waves each)
#define VLEN    160      // V = [x(39)+pad(1) | h(100) | zero-pad(20)]
#define CHUNK   52       // floats per part = 13 float4

__device__ __forceinline__ float fast_sigmoid(float v) {
    return 1.f / (1.f + __expf(-v));
}
__device__ __forceinline__ float fast_tanh(float v) {
    const float c = fminf(fmaxf(v, -15.f), 15.f);
    const float e = __expf(2.f * c);
    return (e - 1.f) / (e + 1.f);
}

// R4-R8 lesson chain: the register allocator ALWAYS remats invariant weight
// loads to chase maximum occupancy (R8: VGPR=48 < the 52 weights, 10 waves/EU
// "achieved" — useless, since 1 block/CU caps us at 4 waves/EU physically).
// __launch_bounds__' 2nd arg is only a MIN waves/EU. The fix is the max:
// amdgpu_waves_per_eu(4,4) pins target occupancy at 4 waves/EU -> VGPR budget
// 128 -> no benefit to remat -> the 52 hoisted weight loads stay resident and
// the K-loop contains zero global loads.
//   p0: V[0:52)   = x(39)+pad (+ zero-weight tail)
//   p1: V[40:92)  = h[0:52)
//   p2: V[92:144) = h[52:100) + zero-pad
__attribute__((amdgpu_waves_per_eu(4, 4)))
__launch_bounds__(NTHR)
__global__ void gru_persistent(const float* __restrict__ mfcc0,
                               const float* __restrict__ mfcc1,
                               const float* __restrict__ mfcc2,
                               const float* __restrict__ len0,
                               const float* __restrict__ W_ih,
                               const float* __restrict__ W_hh,
                               const float* __restrict__ b_ih,
                               const float* __restrict__ b_hh,
                               const float* __restrict__ W_out,
                               const float* __restrict__ b_out,
                               float* __restrict__ out)
{
    const int b   = blockIdx.x;
    const int tid = threadIdx.x;
    const int p   = tid / 320;                    // part 0,1,2 (wave-aligned)
    const int g0  = tid % 320;                    // row id within part
    const int g   = (g0 < G3) ? g0 : (G3 - 1);    // clamped; stores guarded by g0

    __shared__ __align__(16) float V[2][VLEN];    // [x | h | pad] ping-pong
    __shared__ float part[3 * G3];                // partial dot per (p, row)
    __shared__ float feat[2 * HDIM];

    // ---- one-time setup (uniform control flow; scalars only — no aggregates) ----
    const float* src = (p == 0) ? (W_ih + g * XDIM)
                                : (W_hh + g * HDIM + ((p == 2) ? CHUNK : 0));
    const int   c    = (p == 0) ? XDIM : ((p == 1) ? CHUNK : (HDIM - CHUNK));
    const float bias = (p == 0) ? b_ih[g] : ((p == 1) ? b_hh[g] : 0.f);
    const int   vb0  = (p == 0) ? 0 : ((p == 1) ? 10 : 23);   // float4-unit base

    float w00 = ( 0 < c) ? src[ 0] : 0.f, w01 = ( 1 < c) ? src[ 1] : 0.f;
    float w02 = ( 2 < c) ? src[ 2] : 0.f, w03 = ( 3 < c) ? src[ 3] : 0.f;
    float w04 = ( 4 < c) ? src[ 4] : 0.f, w05 = ( 5 < c) ? src[ 5] : 0.f;
    float w06 = ( 6 < c) ? src[ 6] : 0.f, w07 = ( 7 < c) ? src[ 7] : 0.f;
    float w08 = ( 8 < c) ? src[ 8] : 0.f, w09 = ( 9 < c) ? src[ 9] : 0.f;
    float w10 = (10 < c) ? src[10] : 0.f, w11 = (11 < c) ? src[11] : 0.f;
    float w12 = (12 < c) ? src[12] : 0.f, w13 = (13 < c) ? src[13] : 0.f;
    float w14 = (14 < c) ? src[14] : 0.f, w15 = (15 < c) ? src[15] : 0.f;
    float w16 = (16 < c) ? src[16] : 0.f, w17 = (17 < c) ? src[17] : 0.f;
    float w18 = (18 < c) ? src[18] : 0.f, w19 = (19 < c) ? src[19] : 0.f;
    float w20 = (20 < c) ? src[20] : 0.f, w21 = (21 < c) ? src[21] : 0.f;
    float w22 = (22 < c) ? src[22] : 0.f, w23 = (23 < c) ? src[23] : 0.f;
    float w24 = (24 < c) ? src[24] : 0.f, w25 = (25 < c) ? src[25] : 0.f;
    float w26 = (26 < c) ? src[26] : 0.f, w27 = (27 < c) ? src[27] : 0.f;
    float w28 = (28 < c) ? src[28] : 0.f, w29 = (29 < c) ? src[29] : 0.f;
    float w30 = (30 < c) ? src[30] : 0.f, w31 = (31 < c) ? src[31] : 0.f;
    float w32 = (32 < c) ? src[32] : 0.f, w33 = (33 < c) ? src[33] : 0.f;
    float w34 = (34 < c) ? src[34] : 0.f, w35 = (35 < c) ? src[35] : 0.f;
    float w36 = (36 < c) ? src[36] : 0.f, w37 = (37 < c) ? src[37] : 0.f;
    float w38 = (38 < c) ? src[38] : 0.f, w39 = (39 < c) ? src[39] : 0.f;
    float w40 = (40 < c) ? src[40] : 0.f, w41 = (41 < c) ? src[41] : 0.f;
    float w42 = (42 < c) ? src[42] : 0.f, w43 = (43 < c) ? src[43] : 0.f;
    float w44 = (44 < c) ? src[44] : 0.f, w45 = (45 < c) ? src[45] : 0.f;
    float w46 = (46 < c) ? src[46] : 0.f, w47 = (47 < c) ? src[47] : 0.f;
    float w48 = (48 < c) ? src[48] : 0.f, w49 = (49 < c) ? src[49] : 0.f;
    float w50 = (50 < c) ? src[50] : 0.f, w51 = (51 < c) ? src[51] : 0.f;

    // ---- per-thread x streaming source (threads 0..38, all in part 0) ----
    const float* xsrc = mfcc0;
    int xoff = 0;
    if (tid < XDIM) {
        const int f = tid % FIN;
        xsrc = (tid < FIN) ? mfcc0 : (tid < 2 * FIN ? mfcc1 : mfcc2);
        xoff = b * FIN + f;
    }

    // ---- init: zero both V buffers (h=0, pads=0), then x(t=0) ----
    if (tid < VLEN) { V[0][tid] = 0.f; V[1][tid] = 0.f; }
    if (tid < XDIM) V[0][tid] = xsrc[xoff];
    __syncthreads();

    float sum = 0.f;
    float mx  = -INFINITY;

    for (int t = 0; t < T_STEPS; ++t) {
        const int cur = t & 1;
        const int nxt = cur ^ 1;

        float xpf = 0.f;   // prefetch x(t+1) during compute
        if (tid < XDIM && (t + 1) < T_STEPS)
            xpf = xsrc[(size_t)(t + 1) * (BATCH * FIN) + xoff];

        // ---- phase A: 13 broadcast float4 reads x 4 FMAs (uniform body) ----
        const float4* V4 = (const float4*)V[cur];
        float a0 = 0.f, a1 = 0.f, a2 = 0.f, a3 = 0.f;
        float4 vv;
        vv = V4[vb0+ 0]; a0=fmaf(w00,vv.x,a0); a1=fmaf(w01,vv.y,a1); a2=fmaf(w02,vv.z,a2); a3=fmaf(w03,vv.w,a3);
        vv = V4[vb0+ 1]; a0=fmaf(w04,vv.x,a0); a1=fmaf(w05,vv.y,a1); a2=fmaf(w06,vv.z,a2); a3=fmaf(w07,vv.w,a3);
        vv = V4[vb0+ 2]; a0=fmaf(w08,vv.x,a0); a1=fmaf(w09,vv.y,a1); a2=fmaf(w10,vv.z,a2); a3=fmaf(w11,vv.w,a3);
        vv = V4[vb0+ 3]; a0=fmaf(w12,vv.x,a0); a1=fmaf(w13,vv.y,a1); a2=fmaf(w14,vv.z,a2); a3=fmaf(w15,vv.w,a3);
        vv = V4[vb0+ 4]; a0=fmaf(w16,vv.x,a0); a1=fmaf(w17,vv.y,a1); a2=fmaf(w18,vv.z,a2); a3=fmaf(w19,vv.w,a3);
        vv = V4[vb0+ 5]; a0=fmaf(w20,vv.x,a0); a1=fmaf(w21,vv.y,a1); a2=fmaf(w22,vv.z,a2); a3=fmaf(w23,vv.w,a3);
        vv = V4[vb0+ 6]; a0=fmaf(w24,vv.x,a0); a1=fmaf(w25,vv.y,a1); a2=fmaf(w26,vv.z,a2); a3=fmaf(w27,vv.w,a3);
        vv = V4[vb0+ 7]; a0=fmaf(w28,vv.x,a0); a1=fmaf(w29,vv.y,a1); a2=fmaf(w30,vv.z,a2); a3=fmaf(w31,vv.w,a3);
        vv = V4[vb0+ 8]; a0=fmaf(w32,vv.x,a0); a1=fmaf(w33,vv.y,a1); a2=fmaf(w34,vv.z,a2); a3=fmaf(w35,vv.w,a3);
        vv = V4[vb0+ 9]; a0=fmaf(w36,vv.x,a0); a1=fmaf(w37,vv.y,a1); a2=fmaf(w38,vv.z,a2); a3=fmaf(w39,vv.w,a3);
        vv = V4[vb0+10]; a0=fmaf(w40,vv.x,a0); a1=fmaf(w41,vv.y,a1); a2=fmaf(w42,vv.z,a2); a3=fmaf(w43,vv.w,a3);
        vv = V4[vb0+11]; a0=fmaf(w44,vv.x,a0); a1=fmaf(w45,vv.y,a1); a2=fmaf(w46,vv.z,a2); a3=fmaf(w47,vv.w,a3);
        vv = V4[vb0+12]; a0=fmaf(w48,vv.x,a0); a1=fmaf(w49,vv.y,a1); a2=fmaf(w50,vv.z,a2); a3=fmaf(w51,vv.w,a3);

        if (g0 < G3)
            part[p * G3 + g0] = bias + ((a0 + a1) + (a2 + a3));
        if (tid < XDIM) V[nxt][tid] = xpf;         // stage x(t+1)
        __syncthreads();

        // ---- phase B: nonlinearity + state update (threads 0..99) ----
        if (tid < HDIM) {
            const float r  = fast_sigmoid(part[tid] + part[G3 + tid] + part[2*G3 + tid]);
            const float z  = fast_sigmoid(part[HDIM + tid] + part[G3 + HDIM + tid] + part[2*G3 + HDIM + tid]);
            const float hn = part[G3 + 2*HDIM + tid] + part[2*G3 + 2*HDIM + tid];  // includes b_hh
            const float n  = fast_tanh(fmaf(r, hn, part[2*HDIM + tid]));           // i_n includes b_ih
            const float ho = V[cur][XDIM + 1 + tid];
            const float hv = fmaf(z, ho - n, n);   // (1-z)*n + z*h
            V[nxt][XDIM + 1 + tid] = hv;
            sum += hv;
            mx = fmaxf(mx, hv);
        }
        __syncthreads();
    }

    // ---- pooling + output linear ----
    if (tid < HDIM) {
        feat[tid]        = sum / len0[b];
        feat[HDIM + tid] = mx;
    }
    __syncthreads();

    if (tid < NCLS) {
        float acc = b_out[tid];
        #pragma unroll 4
        for (int k = 0; k < 2 * HDIM; ++k)
            acc = fmaf(W_out[tid * 2 * HDIM + k], feat[k], acc);
        out[b * NCLS + tid] = acc;
    }
}

extern "C" void kernel_launch(void* const* d_in, const int* in_sizes, int n_in,
                              void* d_out, int out_size, void* d_ws, size_t ws_size,
                              hipStream_t stream)
{
    const float* mfcc0 = (const float*)d_in[0];
    const float* mfcc1 = (const float*)d_in[1];
    const float* mfcc2 = (const float*)d_in[2];
    const float* len0  = (const float*)d_in[3];
    const float* W_ih  = (const float*)d_in[4];
    const float* W_hh  = (const float*)d_in[5];
    const float* b_ih  = (const float*)d_in[6];
    const float* b_hh  = (const float*)d_in[7];
    const float* W_out = (const float*)d_in[8];
    const float* b_out = (const float*)d_in[9];
    float* out = (float*)d_out;

    gru_persistent<<<BATCH, NTHR, 0, stream>>>(
        mfcc0, mfcc1, mfcc2, len0, W_ih, W_hh, b_ih, b_hh, W_out, b_out, out);
}